// Round 7
// baseline (231.545 us; speedup 1.0000x reference)
//
#include <hip/hip_runtime.h>
#include <hip/hip_bf16.h>

// MoE: N=8192 tokens, D=1024, E=8 experts, top-2 routing.
// Inputs (fp32): x[8192,1024], Wr[1024,8], br[8], W[8,1024,1024], b[8,1024]
// Output (fp32): out[8192,1024]
//
// R1: block-aggregated scatter. R2: dense tile list. R3: split-K regressed.
// R4: atomic-free epilogue (slot-major bf16 ybuf + combine), eff. BK=64.
// R5: fusion 6->3. R6: router parallelism (null). R7/R8: tr_b16 absmax FAIL,
//     reverted. R9: 512B-segment transpose (null). R10: split router/wcast
//     (visibility; all small kernels < 62us each).
// R11: GEMM pipeline upgrade (the one kernel rocprof can see):
//  (a) 2-phase double-buffered K-loop, counted-wait style: STAGE(t+1) issued
//      before compute(t); ONE vmcnt(0)+s_barrier per K-step (was: full drain
//      + 2 barriers with zero overlap).
//  (b) XCD-aware block remap: a tile's 8 n-blocks get linear ids = c (mod 8)
//      so they share one XCD's L2 -> xbf A-panel fetched once, not 8x
//      (FETCH 118MB was 16wt + 8x16 xbf).
//  Router/wcast/combine byte-identical (control).

#define NTOK 8192
#define DM   1024
#define NEXP 8
#define CAP  8192    // per-expert slot capacity (worst case)
#define MAXT 136     // max total m-tiles (must be multiple of 8 for remap)

#define RBLK 1024    // router blocks (8 tokens each)
#define WBLK 512     // wcast blocks (128d x 128h tiles): 8e * 8d * 8h

typedef __attribute__((ext_vector_type(8))) short bf16x8;
typedef __attribute__((ext_vector_type(4))) float f32x4;

__device__ __forceinline__ unsigned short f2bf(float f) {
  unsigned u = __float_as_uint(f);
  unsigned r = (u + 0x7fffu + ((u >> 16) & 1u)) >> 16;
  return (unsigned short)r;
}
__device__ __forceinline__ float bf2f(unsigned short s) {
  return __uint_as_float(((unsigned)s) << 16);
}

__device__ __forceinline__ void gl_lds16(const void* g, void* l) {
  __builtin_amdgcn_global_load_lds(
      (const __attribute__((address_space(1))) unsigned int*)g,
      (__attribute__((address_space(3))) unsigned int*)l, 16, 0, 0);
}

// ---------------- Router: logits, top-2, gates, xbf cast, scatter ----------
// (R10 form, unchanged.)
__global__ __launch_bounds__(256) void router_kernel(
    const float* __restrict__ x, const float* __restrict__ Wr,
    const float* __restrict__ br, unsigned short* __restrict__ xbf,
    int4* __restrict__ topk, int* __restrict__ counts,
    int* __restrict__ tok, int2* __restrict__ pos,
    int* __restrict__ done, int* __restrict__ desc,
    int* __restrict__ ntiles, int* __restrict__ offset) {
  __shared__ int lcnt[NEXP];
  __shared__ int4 ltop[8];
  __shared__ int2 lrank[8];
  const int tid = threadIdx.x;
  const int rb = blockIdx.x;
  const int wave = tid >> 6, lane = tid & 63;
  const int tb = rb * 8 + wave * 2;   // this wave's 2 tokens
  if (tid < NEXP) lcnt[tid] = 0;

  const int l4 = lane * 4;

  float v[2][16];
#pragma unroll
  for (int tt = 0; tt < 2; tt++) {
#pragma unroll
    for (int i = 0; i < 4; i++) {
      float4 f = *(const float4*)(x + (size_t)(tb + tt) * DM + i * 256 + l4);
      v[tt][i * 4 + 0] = f.x; v[tt][i * 4 + 1] = f.y;
      v[tt][i * 4 + 2] = f.z; v[tt][i * 4 + 3] = f.w;
    }
  }
#pragma unroll
  for (int tt = 0; tt < 2; tt++) {
#pragma unroll
    for (int i = 0; i < 4; i++) {
      uint2 pk;
      pk.x = (unsigned)f2bf(v[tt][i * 4 + 0]) |
             ((unsigned)f2bf(v[tt][i * 4 + 1]) << 16);
      pk.y = (unsigned)f2bf(v[tt][i * 4 + 2]) |
             ((unsigned)f2bf(v[tt][i * 4 + 3]) << 16);
      *(uint2*)(xbf + (size_t)(tb + tt) * DM + i * 256 + l4) = pk;
    }
  }
  float p[2][8] = {};
#pragma unroll
  for (int i = 0; i < 4; i++) {
#pragma unroll
    for (int j = 0; j < 4; j++) {
      const float* wrow = Wr + (size_t)(i * 256 + l4 + j) * NEXP;
      float4 wl = *(const float4*)(wrow);
      float4 wh = *(const float4*)(wrow + 4);
#pragma unroll
      for (int tt = 0; tt < 2; tt++) {
        float xv = v[tt][i * 4 + j];
        p[tt][0] += xv * wl.x; p[tt][1] += xv * wl.y;
        p[tt][2] += xv * wl.z; p[tt][3] += xv * wl.w;
        p[tt][4] += xv * wh.x; p[tt][5] += xv * wh.y;
        p[tt][6] += xv * wh.z; p[tt][7] += xv * wh.w;
      }
    }
  }
#pragma unroll
  for (int off = 32; off >= 1; off >>= 1) {
#pragma unroll
    for (int tt = 0; tt < 2; tt++)
#pragma unroll
      for (int e = 0; e < 8; e++)
        p[tt][e] += __shfl_xor(p[tt][e], off, 64);
  }
  if (lane == 0) {
#pragma unroll
    for (int tt = 0; tt < 2; tt++) {
      float lg[8];
#pragma unroll
      for (int e = 0; e < 8; e++) lg[e] = p[tt][e] + br[e];
      float v0 = lg[0]; int i0 = 0;
#pragma unroll
      for (int e = 1; e < 8; e++) if (lg[e] > v0) { v0 = lg[e]; i0 = e; }
      float v1 = -3.4e38f; int i1 = 0;
#pragma unroll
      for (int e = 0; e < 8; e++)
        if (e != i0 && lg[e] > v1) { v1 = lg[e]; i1 = e; }
      float ee = __expf(v1 - v0);
      float g0 = 1.0f / (1.0f + ee);
      float g1 = ee / (1.0f + ee);
      int4 rec;
      rec.x = i0; rec.y = i1;
      rec.z = __float_as_int(g0); rec.w = __float_as_int(g1);
      ltop[wave * 2 + tt] = rec;
      topk[tb + tt] = rec;
    }
  }
  __syncthreads();

  if (tid < 8) {
    int4 r = ltop[tid];
    int s0 = atomicAdd(&lcnt[r.x], 1);
    int s1 = atomicAdd(&lcnt[r.y], 1);
    int2 rk; rk.x = s0; rk.y = s1;
    lrank[tid] = rk;
  }
  __syncthreads();
  if (tid < NEXP) lcnt[tid] = atomicAdd(&counts[tid], lcnt[tid]);
  __syncthreads();
  if (tid < 8) {
    int4 r = ltop[tid];
    int2 rk = lrank[tid];
    int p0 = lcnt[r.x] + rk.x;
    int p1 = lcnt[r.y] + rk.y;
    int t = rb * 8 + tid;
    tok[r.x * CAP + p0] = t;
    tok[r.y * CAP + p1] = t;
    int2 pr; pr.x = p0; pr.y = p1;
    pos[t] = pr;
  }
  __syncthreads();

  if (tid == 0) {
    __threadfence();
    if (atomicAdd(done, 1) == RBLK - 1) {
      __threadfence();
      int cnt[NEXP];
#pragma unroll
      for (int e = 0; e < NEXP; e++) cnt[e] = atomicAdd(&counts[e], 0);
      int idx = 0, off = 0;
#pragma unroll
      for (int e = 0; e < NEXP; e++) {
        offset[e] = off;
        off += cnt[e];
        int nm = (cnt[e] + 127) >> 7;
        for (int i = 0; i < nm; i++) desc[idx++] = (e << 16) | i;
      }
      *ntiles = idx;
    }
  }
}

// ---------------- W transpose + bf16 cast (R10 form, unchanged) ------------
__global__ __launch_bounds__(256) void wcast_kernel(
    const float* __restrict__ W, unsigned short* __restrict__ Wt) {
  __shared__ __align__(16) unsigned int smem[8192];  // 32 KB
  const int tid = threadIdx.x;
  const int tb = blockIdx.x;
  const int e = tb >> 6;
  const int rem = tb & 63;
  const int D0 = (rem >> 3) * 128;
  const int H0 = (rem & 7) * 128;

  const int dp = tid >> 5;          // 0..7
  const int c  = tid & 31;          // 0..31
  const float* Wsrc = W + (size_t)e * DM * DM + (size_t)D0 * DM + H0 + c * 4;
#pragma unroll 4
  for (int i = 0; i < 8; i++) {
    const int dc = dp + 8 * i;      // dword col 0..63 (d = 2dc, 2dc+1)
    const int d = dc * 2;
    float4 a = *(const float4*)(Wsrc + (size_t)d * DM);
    float4 b = *(const float4*)(Wsrc + (size_t)(d + 1) * DM);
    unsigned pk[4];
    pk[0] = (unsigned)f2bf(a.x) | ((unsigned)f2bf(b.x) << 16);
    pk[1] = (unsigned)f2bf(a.y) | ((unsigned)f2bf(b.y) << 16);
    pk[2] = (unsigned)f2bf(a.z) | ((unsigned)f2bf(b.z) << 16);
    pk[3] = (unsigned)f2bf(a.w) | ((unsigned)f2bf(b.w) << 16);
#pragma unroll
    for (int j = 0; j < 4; j++) {
      const int h = c * 4 + j;                       // 0..127
      const int pg = ((dc >> 2) ^ (h >> 2)) & 15;    // swizzled granule
      smem[h * 64 + pg * 4 + (dc & 3)] = pk[j];
    }
  }
  __syncthreads();

  const int hh = tid >> 4;   // 0..15
  const int g  = tid & 15;   // logical granule (8 bf16 of d)
  unsigned short* Wdst = Wt + (size_t)e * DM * DM + (size_t)H0 * DM + D0;
#pragma unroll 4
  for (int o = 0; o < 8; o++) {
    const int h = hh + 16 * o;                       // 0..127
    const int pg = (g ^ (h >> 2)) & 15;              // physical granule
    uint4 v = *(const uint4*)(smem + h * 64 + pg * 4);
    *(uint4*)(Wdst + (size_t)h * DM + g * 8) = v;
  }
}

// ---------------- Routed expert GEMM -> slot-major bf16 ybuf ----------------
// Tile 128x128, BK=64, 4 waves 2x2. R11: 2-phase double-buffered K-loop
// (STAGE(t+1) issued before compute(t), single vmcnt(0)+s_barrier per step)
// + XCD-aware block remap (a tile's 8 n-blocks share one XCD's L2).
__global__ __launch_bounds__(256) void moe_gemm_kernel(
    const unsigned short* __restrict__ xbf, const unsigned short* __restrict__ wt,
    const int* __restrict__ counts, const int* __restrict__ offset,
    const int* __restrict__ tok, const int* __restrict__ desc,
    const int* __restrict__ ntiles, unsigned short* __restrict__ ybuf) {
  // remap: linear L -> slot=(L&7)+8*(L>>6), nb=(L>>3)&7. Bijective on [0,1088).
  // The 8 n-blocks of a slot have ids congruent mod 8 -> same XCD (round-robin),
  // so the slot's xbf A-panel (256KB) is fetched once into that XCD's L2.
  const int L = blockIdx.y * 8 + blockIdx.x;
  const int slot = (L & 7) | ((L >> 6) << 3);
  const int n0 = ((L >> 3) & 7) * 128;
  if (slot >= *ntiles) return;
  const int dsc = desc[slot];
  const int e = dsc >> 16;
  const int m0 = (dsc & 0xffff) * 128;
  const int cnt = counts[e];

  // double-buffered LDS: [buf][khalf][128 rows x 32 k] for A and B (64 KB)
  __shared__ __align__(16) unsigned short sA[2][2][128 * 32];
  __shared__ __align__(16) unsigned short sB[2][2][128 * 32];
  __shared__ int sTok[128];

  const int tid = threadIdx.x, wave = tid >> 6, lane = tid & 63;

  if (tid < 128) {
    int sr = m0 + tid;
    int cl = (sr < cnt) ? sr : (cnt - 1);
    sTok[tid] = tok[e * CAP + cl];
  }
  __syncthreads();

  // staging: wave w stages 16-row groups {w, w+4}; lane i -> row g*16+(i>>2),
  // chunk slot i&3; source chunk XOR-swizzled (2-way LDS aliasing = free).
  const int rA1 = wave * 16 + (lane >> 2);
  const int rA2 = rA1 + 64;
  const int cch = lane & 3;
  const int cg1 = (cch ^ ((rA1 >> 1) & 3)) * 8;  // elements
  const int cg2 = (cch ^ ((rA2 >> 1) & 3)) * 8;
  const unsigned short* pA1 = xbf + (size_t)sTok[rA1] * DM + cg1;
  const unsigned short* pA2 = xbf + (size_t)sTok[rA2] * DM + cg2;
  const unsigned short* wte = wt + (size_t)e * DM * DM;
  const unsigned short* pB1 = wte + (size_t)(n0 + rA1) * DM + cg1;
  const unsigned short* pB2 = wte + (size_t)(n0 + rA2) * DM + cg2;
  const int lo1 = wave * 512, lo2 = (wave + 4) * 512;  // 1KB per 16-row group

  const int q = lane >> 4, ml = lane & 15;
  const int wm = (wave >> 1) * 64, wn = (wave & 1) * 64;
  int offA[4], offB[4];
#pragma unroll
  for (int i = 0; i < 4; i++) {
    int row = wm + i * 16 + ml;
    offA[i] = row * 32 + (q ^ ((row >> 1) & 3)) * 8;
    int rowb = wn + i * 16 + ml;
    offB[i] = rowb * 32 + (q ^ ((rowb >> 1) & 3)) * 8;
  }

#define STAGE(b, kk)                                  \
  do {                                                \
    gl_lds16(pA1 + (kk),      &sA[b][0][lo1]);        \
    gl_lds16(pA2 + (kk),      &sA[b][0][lo2]);        \
    gl_lds16(pB1 + (kk),      &sB[b][0][lo1]);        \
    gl_lds16(pB2 + (kk),      &sB[b][0][lo2]);        \
    gl_lds16(pA1 + (kk) + 32, &sA[b][1][lo1]);        \
    gl_lds16(pA2 + (kk) + 32, &sA[b][1][lo2]);        \
    gl_lds16(pB1 + (kk) + 32, &sB[b][1][lo1]);        \
    gl_lds16(pB2 + (kk) + 32, &sB[b][1][lo2]);        \
  } while (0)

  f32x4 acc[4][4] = {};

  // prologue: stage first K-tile, drain, join
  STAGE(0, 0);
  asm volatile("s_waitcnt vmcnt(0)" ::: "memory");
  __builtin_amdgcn_s_barrier();

  int cur = 0;
  for (int k0 = 0; k0 < DM; k0 += 64) {
    // issue next K-tile's stage early (overlaps with compute below)
    if (k0 + 64 < DM) STAGE(cur ^ 1, k0 + 64);
    __builtin_amdgcn_sched_barrier(0);  // pin stage issue above compute

    const unsigned short* a0 = sA[cur][0];
    const unsigned short* b0 = sB[cur][0];
    const unsigned short* a1 = sA[cur][1];
    const unsigned short* b1 = sB[cur][1];
    bf16x8 af0[4], bf0[4], af1[4], bf1[4];
#pragma unroll
    for (int i = 0; i < 4; i++) {
      af0[i] = *(const bf16x8*)(a0 + offA[i]);
      bf0[i] = *(const bf16x8*)(b0 + offB[i]);
      af1[i] = *(const bf16x8*)(a1 + offA[i]);
      bf1[i] = *(const bf16x8*)(b1 + offB[i]);
    }
#pragma unroll
    for (int mt = 0; mt < 4; mt++)
#pragma unroll
      for (int nt = 0; nt < 4; nt++)
        acc[mt][nt] = __builtin_amdgcn_mfma_f32_16x16x32_bf16(
            af0[mt], bf0[nt], acc[mt][nt], 0, 0, 0);
#pragma unroll
    for (int mt = 0; mt < 4; mt++)
#pragma unroll
      for (int nt = 0; nt < 4; nt++)
        acc[mt][nt] = __builtin_amdgcn_mfma_f32_16x16x32_bf16(
            af1[mt], bf1[nt], acc[mt][nt], 0, 0, 0);

    // one drain+barrier per K-step:
    //  - vmcnt(0): my next-tile stage writes landed
    //  - barrier: everyone's stage landed AND everyone's reads of cur done
    asm volatile("s_waitcnt vmcnt(0)" ::: "memory");
    __builtin_amdgcn_s_barrier();
    cur ^= 1;
  }
#undef STAGE

  // epilogue: plain bf16 stores of raw accumulators (slot-major)
  const int yb = offset[e] + m0;
#pragma unroll
  for (int mt = 0; mt < 4; mt++) {
    int rbase = wm + mt * 16 + q * 4;
#pragma unroll
    for (int r = 0; r < 4; r++) {
      int row = rbase + r;
      if (m0 + row >= cnt) continue;
      unsigned short* yrow = ybuf + (size_t)(yb + row) * DM + n0;
#pragma unroll
      for (int nt = 0; nt < 4; nt++) {
        yrow[wn + nt * 16 + ml] = f2bf(acc[mt][nt][r]);
      }
    }
  }
}

// ---------------- Combine: out[t] = g0*(y0+b[e0]) + g1*(y1+b[e1]) -----------
__global__ __launch_bounds__(256) void combine_kernel(
    const unsigned short* __restrict__ ybuf, const int4* __restrict__ topk,
    const int2* __restrict__ pos, const int* __restrict__ offset,
    const float* __restrict__ bias, float* __restrict__ out) {
  const int c = threadIdx.x * 4;
  const int t0 = blockIdx.x * 4;
#pragma unroll
  for (int i = 0; i < 4; i++) {
    const int t = t0 + i;
    int4 r = topk[t];
    int2 p = pos[t];
    float g0 = __int_as_float(r.z), g1 = __int_as_float(r.w);
    int s0 = offset[r.x] + p.x;
    int s1 = offset[r.y] + p.y;
    ushort4 ya = *(const ushort4*)(ybuf + (size_t)s0 * DM + c);
    ushort4 yb = *(const ushort4*)(ybuf + (size_t)s1 * DM + c);
    float4 b0 = *(const float4*)(bias + (size_t)r.x * DM + c);
    float4 b1 = *(const float4*)(bias + (size_t)r.y * DM + c);
    float4 o;
    o.x = g0 * (bf2f(ya.x) + b0.x) + g1 * (bf2f(yb.x) + b1.x);
    o.y = g0 * (bf2f(ya.y) + b0.y) + g1 * (bf2f(yb.y) + b1.y);
    o.z = g0 * (bf2f(ya.z) + b0.z) + g1 * (bf2f(yb.z) + b1.z);
    o.w = g0 * (bf2f(ya.w) + b0.w) + g1 * (bf2f(yb.w) + b1.w);
    *(float4*)(out + (size_t)t * DM + c) = o;
  }
}

extern "C" void kernel_launch(void* const* d_in, const int* in_sizes, int n_in,
                              void* d_out, int out_size, void* d_ws, size_t ws_size,
                              hipStream_t stream) {
  const float* x  = (const float*)d_in[0];
  const float* Wr = (const float*)d_in[1];
  const float* br = (const float*)d_in[2];
  const float* W  = (const float*)d_in[3];
  const float* b  = (const float*)d_in[4];
  float* out = (float*)d_out;

  // workspace layout (~65.5 MB)
  char* ws = (char*)d_ws;
  unsigned short* xbf  = (unsigned short*)ws;                       // 16 MB
  unsigned short* wt   = (unsigned short*)(ws + (16u << 20));       // 16 MB
  unsigned short* ybuf = (unsigned short*)(ws + (32u << 20));       // 32 MB
  char* ctrl = ws + (64u << 20);
  int*   counts = (int*)ctrl;                                       // 32 B
  int*   ntiles = (int*)(ctrl + 64);                                // 4 B
  int*   done   = (int*)(ctrl + 96);                                // 4 B
  int*   offset = (int*)(ctrl + 128);                               // 32 B
  int*   desc   = (int*)(ctrl + 256);                               // 544 B
  int*   tok    = (int*)(ctrl + 4096);                              // 256 KB
  int2*  pos    = (int2*)(ctrl + 4096 + (256u << 10));              // 64 KB
  int4*  topk   = (int4*)(ctrl + 4096 + (320u << 10));              // 128 KB

  hipMemsetAsync(ctrl, 0, 128, stream);  // counts + ntiles + done

  router_kernel<<<RBLK, 256, 0, stream>>>(
      x, Wr, br, xbf, topk, counts, tok, pos, done, desc, ntiles, offset);
  wcast_kernel<<<WBLK, 256, 0, stream>>>(W, wt);
  moe_gemm_kernel<<<dim3(8, MAXT), 256, 0, stream>>>(
      xbf, wt, counts, offset, tok, desc, ntiles, ybuf);
  combine_kernel<<<NTOK / 4, 256, 0, stream>>>(ybuf, topk, pos, offset, b, out);
}

// Round 8
// 229.408 us; speedup vs baseline: 1.0093x; 1.0093x over previous
//
#include <hip/hip_runtime.h>
#include <hip/hip_bf16.h>

// MoE: N=8192 tokens, D=1024, E=8 experts, top-2 routing.
// Inputs (fp32): x[8192,1024], Wr[1024,8], br[8], W[8,1024,1024], b[8,1024]
// Output (fp32): out[8192,1024]
//
// R1: block-aggregated scatter. R2: dense tile list. R3: split-K regressed.
// R4: atomic-free epilogue (slot-major bf16 ybuf + combine), eff. BK=64.
// R5: fusion 6->3. R6: router parallelism (null). R7/R8: tr_b16 absmax FAIL,
//     reverted. R9: 512B-segment transpose (null). R10: split router/wcast.
// R11: 2-phase dbuf GEMM: REGRESSED 62->70 (LDS 66KB halved residency to
//     2 blk/CU; occupancy 21->15) BUT XCD remap WORKED: FETCH 118->85.5MB.
// R12: (a) GEMM core reverted to proven R4 schedule (33KB LDS, 4 blk/CU),
//     KEEPING the XCD remap. (b) GEMM split into two launches (slots 0-63 /
//     64-135) to lower the top-5 waterline to ~30us: hidden kernels
//     (router/wcast/combine — never yet measured in 8 rounds) must surface
//     in top-5 with counters if they exceed ~30us. Measurement recovery.

#define NTOK 8192
#define DM   1024
#define NEXP 8
#define CAP  8192    // per-expert slot capacity (worst case)
#define MAXT 136     // max total m-tiles

#define RBLK 1024    // router blocks (8 tokens each)
#define WBLK 512     // wcast blocks (128d x 128h tiles): 8e * 8d * 8h

typedef __attribute__((ext_vector_type(8))) short bf16x8;
typedef __attribute__((ext_vector_type(4))) float f32x4;

__device__ __forceinline__ unsigned short f2bf(float f) {
  unsigned u = __float_as_uint(f);
  unsigned r = (u + 0x7fffu + ((u >> 16) & 1u)) >> 16;
  return (unsigned short)r;
}
__device__ __forceinline__ float bf2f(unsigned short s) {
  return __uint_as_float(((unsigned)s) << 16);
}

__device__ __forceinline__ void gl_lds16(const void* g, void* l) {
  __builtin_amdgcn_global_load_lds(
      (const __attribute__((address_space(1))) unsigned int*)g,
      (__attribute__((address_space(3))) unsigned int*)l, 16, 0, 0);
}

// ---------------- Router: logits, top-2, gates, xbf cast, scatter ----------
// (R10 form, unchanged.)
__global__ __launch_bounds__(256) void router_kernel(
    const float* __restrict__ x, const float* __restrict__ Wr,
    const float* __restrict__ br, unsigned short* __restrict__ xbf,
    int4* __restrict__ topk, int* __restrict__ counts,
    int* __restrict__ tok, int2* __restrict__ pos,
    int* __restrict__ done, int* __restrict__ desc,
    int* __restrict__ ntiles, int* __restrict__ offset) {
  __shared__ int lcnt[NEXP];
  __shared__ int4 ltop[8];
  __shared__ int2 lrank[8];
  const int tid = threadIdx.x;
  const int rb = blockIdx.x;
  const int wave = tid >> 6, lane = tid & 63;
  const int tb = rb * 8 + wave * 2;   // this wave's 2 tokens
  if (tid < NEXP) lcnt[tid] = 0;

  const int l4 = lane * 4;

  float v[2][16];
#pragma unroll
  for (int tt = 0; tt < 2; tt++) {
#pragma unroll
    for (int i = 0; i < 4; i++) {
      float4 f = *(const float4*)(x + (size_t)(tb + tt) * DM + i * 256 + l4);
      v[tt][i * 4 + 0] = f.x; v[tt][i * 4 + 1] = f.y;
      v[tt][i * 4 + 2] = f.z; v[tt][i * 4 + 3] = f.w;
    }
  }
#pragma unroll
  for (int tt = 0; tt < 2; tt++) {
#pragma unroll
    for (int i = 0; i < 4; i++) {
      uint2 pk;
      pk.x = (unsigned)f2bf(v[tt][i * 4 + 0]) |
             ((unsigned)f2bf(v[tt][i * 4 + 1]) << 16);
      pk.y = (unsigned)f2bf(v[tt][i * 4 + 2]) |
             ((unsigned)f2bf(v[tt][i * 4 + 3]) << 16);
      *(uint2*)(xbf + (size_t)(tb + tt) * DM + i * 256 + l4) = pk;
    }
  }
  float p[2][8] = {};
#pragma unroll
  for (int i = 0; i < 4; i++) {
#pragma unroll
    for (int j = 0; j < 4; j++) {
      const float* wrow = Wr + (size_t)(i * 256 + l4 + j) * NEXP;
      float4 wl = *(const float4*)(wrow);
      float4 wh = *(const float4*)(wrow + 4);
#pragma unroll
      for (int tt = 0; tt < 2; tt++) {
        float xv = v[tt][i * 4 + j];
        p[tt][0] += xv * wl.x; p[tt][1] += xv * wl.y;
        p[tt][2] += xv * wl.z; p[tt][3] += xv * wl.w;
        p[tt][4] += xv * wh.x; p[tt][5] += xv * wh.y;
        p[tt][6] += xv * wh.z; p[tt][7] += xv * wh.w;
      }
    }
  }
#pragma unroll
  for (int off = 32; off >= 1; off >>= 1) {
#pragma unroll
    for (int tt = 0; tt < 2; tt++)
#pragma unroll
      for (int e = 0; e < 8; e++)
        p[tt][e] += __shfl_xor(p[tt][e], off, 64);
  }
  if (lane == 0) {
#pragma unroll
    for (int tt = 0; tt < 2; tt++) {
      float lg[8];
#pragma unroll
      for (int e = 0; e < 8; e++) lg[e] = p[tt][e] + br[e];
      float v0 = lg[0]; int i0 = 0;
#pragma unroll
      for (int e = 1; e < 8; e++) if (lg[e] > v0) { v0 = lg[e]; i0 = e; }
      float v1 = -3.4e38f; int i1 = 0;
#pragma unroll
      for (int e = 0; e < 8; e++)
        if (e != i0 && lg[e] > v1) { v1 = lg[e]; i1 = e; }
      float ee = __expf(v1 - v0);
      float g0 = 1.0f / (1.0f + ee);
      float g1 = ee / (1.0f + ee);
      int4 rec;
      rec.x = i0; rec.y = i1;
      rec.z = __float_as_int(g0); rec.w = __float_as_int(g1);
      ltop[wave * 2 + tt] = rec;
      topk[tb + tt] = rec;
    }
  }
  __syncthreads();

  if (tid < 8) {
    int4 r = ltop[tid];
    int s0 = atomicAdd(&lcnt[r.x], 1);
    int s1 = atomicAdd(&lcnt[r.y], 1);
    int2 rk; rk.x = s0; rk.y = s1;
    lrank[tid] = rk;
  }
  __syncthreads();
  if (tid < NEXP) lcnt[tid] = atomicAdd(&counts[tid], lcnt[tid]);
  __syncthreads();
  if (tid < 8) {
    int4 r = ltop[tid];
    int2 rk = lrank[tid];
    int p0 = lcnt[r.x] + rk.x;
    int p1 = lcnt[r.y] + rk.y;
    int t = rb * 8 + tid;
    tok[r.x * CAP + p0] = t;
    tok[r.y * CAP + p1] = t;
    int2 pr; pr.x = p0; pr.y = p1;
    pos[t] = pr;
  }
  __syncthreads();

  if (tid == 0) {
    __threadfence();
    if (atomicAdd(done, 1) == RBLK - 1) {
      __threadfence();
      int cnt[NEXP];
#pragma unroll
      for (int e = 0; e < NEXP; e++) cnt[e] = atomicAdd(&counts[e], 0);
      int idx = 0, off = 0;
#pragma unroll
      for (int e = 0; e < NEXP; e++) {
        offset[e] = off;
        off += cnt[e];
        int nm = (cnt[e] + 127) >> 7;
        for (int i = 0; i < nm; i++) desc[idx++] = (e << 16) | i;
      }
      *ntiles = idx;
    }
  }
}

// ---------------- W transpose + bf16 cast (R10 form, unchanged) ------------
__global__ __launch_bounds__(256) void wcast_kernel(
    const float* __restrict__ W, unsigned short* __restrict__ Wt) {
  __shared__ __align__(16) unsigned int smem[8192];  // 32 KB
  const int tid = threadIdx.x;
  const int tb = blockIdx.x;
  const int e = tb >> 6;
  const int rem = tb & 63;
  const int D0 = (rem >> 3) * 128;
  const int H0 = (rem & 7) * 128;

  const int dp = tid >> 5;          // 0..7
  const int c  = tid & 31;          // 0..31
  const float* Wsrc = W + (size_t)e * DM * DM + (size_t)D0 * DM + H0 + c * 4;
#pragma unroll 4
  for (int i = 0; i < 8; i++) {
    const int dc = dp + 8 * i;      // dword col 0..63 (d = 2dc, 2dc+1)
    const int d = dc * 2;
    float4 a = *(const float4*)(Wsrc + (size_t)d * DM);
    float4 b = *(const float4*)(Wsrc + (size_t)(d + 1) * DM);
    unsigned pk[4];
    pk[0] = (unsigned)f2bf(a.x) | ((unsigned)f2bf(b.x) << 16);
    pk[1] = (unsigned)f2bf(a.y) | ((unsigned)f2bf(b.y) << 16);
    pk[2] = (unsigned)f2bf(a.z) | ((unsigned)f2bf(b.z) << 16);
    pk[3] = (unsigned)f2bf(a.w) | ((unsigned)f2bf(b.w) << 16);
#pragma unroll
    for (int j = 0; j < 4; j++) {
      const int h = c * 4 + j;                       // 0..127
      const int pg = ((dc >> 2) ^ (h >> 2)) & 15;    // swizzled granule
      smem[h * 64 + pg * 4 + (dc & 3)] = pk[j];
    }
  }
  __syncthreads();

  const int hh = tid >> 4;   // 0..15
  const int g  = tid & 15;   // logical granule (8 bf16 of d)
  unsigned short* Wdst = Wt + (size_t)e * DM * DM + (size_t)H0 * DM + D0;
#pragma unroll 4
  for (int o = 0; o < 8; o++) {
    const int h = hh + 16 * o;                       // 0..127
    const int pg = (g ^ (h >> 2)) & 15;              // physical granule
    uint4 v = *(const uint4*)(smem + h * 64 + pg * 4);
    *(uint4*)(Wdst + (size_t)h * DM + g * 8) = v;
  }
}

// ---------------- Routed expert GEMM -> slot-major bf16 ybuf ----------------
// PROVEN R4 core (33KB LDS, 4 blk/CU) + XCD remap (R11, FETCH 118->85MB).
// slot_base splits the grid into two launches (waterline measurement).
__global__ __launch_bounds__(256) void moe_gemm_kernel(
    const unsigned short* __restrict__ xbf, const unsigned short* __restrict__ wt,
    const int* __restrict__ counts, const int* __restrict__ offset,
    const int* __restrict__ tok, const int* __restrict__ desc,
    const int* __restrict__ ntiles, unsigned short* __restrict__ ybuf,
    int slot_base) {
  // remap: linear L -> slot=(L&7)+8*(L>>6) (+base), nb=(L>>3)&7. The 8
  // n-blocks of a slot have ids congruent mod 8 -> same XCD -> the slot's
  // xbf A-panel is fetched once into that XCD's L2.
  const int L = blockIdx.y * 8 + blockIdx.x;
  const int slot = ((L & 7) | ((L >> 6) << 3)) + slot_base;
  const int n0 = ((L >> 3) & 7) * 128;
  if (slot >= *ntiles) return;
  const int dsc = desc[slot];
  const int e = dsc >> 16;
  const int m0 = (dsc & 0xffff) * 128;
  const int cnt = counts[e];

  __shared__ __align__(16) unsigned short sA0[128 * 32];
  __shared__ __align__(16) unsigned short sB0[128 * 32];
  __shared__ __align__(16) unsigned short sA1[128 * 32];
  __shared__ __align__(16) unsigned short sB1[128 * 32];
  __shared__ int sTok[128];

  const int tid = threadIdx.x, wave = tid >> 6, lane = tid & 63;

  if (tid < 128) {
    int sr = m0 + tid;
    int cl = (sr < cnt) ? sr : (cnt - 1);
    sTok[tid] = tok[e * CAP + cl];
  }
  __syncthreads();

  // staging: wave w stages 16-row groups {w, w+4}; lane i -> row g*16+(i>>2),
  // chunk slot i&3; source chunk XOR-swizzled (2-way LDS aliasing = free).
  const int rA1 = wave * 16 + (lane >> 2);
  const int rA2 = rA1 + 64;
  const int cch = lane & 3;
  const int cg1 = (cch ^ ((rA1 >> 1) & 3)) * 8;  // elements
  const int cg2 = (cch ^ ((rA2 >> 1) & 3)) * 8;
  const unsigned short* pA1 = xbf + (size_t)sTok[rA1] * DM + cg1;
  const unsigned short* pA2 = xbf + (size_t)sTok[rA2] * DM + cg2;
  const unsigned short* wte = wt + (size_t)e * DM * DM;
  const unsigned short* pB1 = wte + (size_t)(n0 + rA1) * DM + cg1;
  const unsigned short* pB2 = wte + (size_t)(n0 + rA2) * DM + cg2;
  const int lo1 = wave * 512, lo2 = (wave + 4) * 512;  // 1KB per 16-row group

  const int q = lane >> 4, ml = lane & 15;
  const int wm = (wave >> 1) * 64, wn = (wave & 1) * 64;
  int offA[4], offB[4];
#pragma unroll
  for (int i = 0; i < 4; i++) {
    int row = wm + i * 16 + ml;
    offA[i] = row * 32 + (q ^ ((row >> 1) & 3)) * 8;
    int rowb = wn + i * 16 + ml;
    offB[i] = rowb * 32 + (q ^ ((rowb >> 1) & 3)) * 8;
  }

  f32x4 acc[4][4] = {};

  for (int k0 = 0; k0 < DM; k0 += 64) {
    // stage both 32-wide k-halves, one barrier
    gl_lds16(pA1 + k0, sA0 + lo1);
    gl_lds16(pA2 + k0, sA0 + lo2);
    gl_lds16(pB1 + k0, sB0 + lo1);
    gl_lds16(pB2 + k0, sB0 + lo2);
    gl_lds16(pA1 + k0 + 32, sA1 + lo1);
    gl_lds16(pA2 + k0 + 32, sA1 + lo2);
    gl_lds16(pB1 + k0 + 32, sB1 + lo1);
    gl_lds16(pB2 + k0 + 32, sB1 + lo2);
    __syncthreads();
    bf16x8 af0[4], bf0[4], af1[4], bf1[4];
#pragma unroll
    for (int i = 0; i < 4; i++) {
      af0[i] = *(const bf16x8*)(sA0 + offA[i]);
      bf0[i] = *(const bf16x8*)(sB0 + offB[i]);
      af1[i] = *(const bf16x8*)(sA1 + offA[i]);
      bf1[i] = *(const bf16x8*)(sB1 + offB[i]);
    }
#pragma unroll
    for (int mt = 0; mt < 4; mt++)
#pragma unroll
      for (int nt = 0; nt < 4; nt++)
        acc[mt][nt] = __builtin_amdgcn_mfma_f32_16x16x32_bf16(
            af0[mt], bf0[nt], acc[mt][nt], 0, 0, 0);
#pragma unroll
    for (int mt = 0; mt < 4; mt++)
#pragma unroll
      for (int nt = 0; nt < 4; nt++)
        acc[mt][nt] = __builtin_amdgcn_mfma_f32_16x16x32_bf16(
            af1[mt], bf1[nt], acc[mt][nt], 0, 0, 0);
    __syncthreads();
  }

  // epilogue: plain bf16 stores of raw accumulators (slot-major)
  const int yb = offset[e] + m0;
#pragma unroll
  for (int mt = 0; mt < 4; mt++) {
    int rbase = wm + mt * 16 + q * 4;
#pragma unroll
    for (int r = 0; r < 4; r++) {
      int row = rbase + r;
      if (m0 + row >= cnt) continue;
      unsigned short* yrow = ybuf + (size_t)(yb + row) * DM + n0;
#pragma unroll
      for (int nt = 0; nt < 4; nt++) {
        yrow[wn + nt * 16 + ml] = f2bf(acc[mt][nt][r]);
      }
    }
  }
}

// ---------------- Combine: out[t] = g0*(y0+b[e0]) + g1*(y1+b[e1]) -----------
__global__ __launch_bounds__(256) void combine_kernel(
    const unsigned short* __restrict__ ybuf, const int4* __restrict__ topk,
    const int2* __restrict__ pos, const int* __restrict__ offset,
    const float* __restrict__ bias, float* __restrict__ out) {
  const int c = threadIdx.x * 4;
  const int t0 = blockIdx.x * 4;
#pragma unroll
  for (int i = 0; i < 4; i++) {
    const int t = t0 + i;
    int4 r = topk[t];
    int2 p = pos[t];
    float g0 = __int_as_float(r.z), g1 = __int_as_float(r.w);
    int s0 = offset[r.x] + p.x;
    int s1 = offset[r.y] + p.y;
    ushort4 ya = *(const ushort4*)(ybuf + (size_t)s0 * DM + c);
    ushort4 yb = *(const ushort4*)(ybuf + (size_t)s1 * DM + c);
    float4 b0 = *(const float4*)(bias + (size_t)r.x * DM + c);
    float4 b1 = *(const float4*)(bias + (size_t)r.y * DM + c);
    float4 o;
    o.x = g0 * (bf2f(ya.x) + b0.x) + g1 * (bf2f(yb.x) + b1.x);
    o.y = g0 * (bf2f(ya.y) + b0.y) + g1 * (bf2f(yb.y) + b1.y);
    o.z = g0 * (bf2f(ya.z) + b0.z) + g1 * (bf2f(yb.z) + b1.z);
    o.w = g0 * (bf2f(ya.w) + b0.w) + g1 * (bf2f(yb.w) + b1.w);
    *(float4*)(out + (size_t)t * DM + c) = o;
  }
}

extern "C" void kernel_launch(void* const* d_in, const int* in_sizes, int n_in,
                              void* d_out, int out_size, void* d_ws, size_t ws_size,
                              hipStream_t stream) {
  const float* x  = (const float*)d_in[0];
  const float* Wr = (const float*)d_in[1];
  const float* br = (const float*)d_in[2];
  const float* W  = (const float*)d_in[3];
  const float* b  = (const float*)d_in[4];
  float* out = (float*)d_out;

  // workspace layout (~65.5 MB)
  char* ws = (char*)d_ws;
  unsigned short* xbf  = (unsigned short*)ws;                       // 16 MB
  unsigned short* wt   = (unsigned short*)(ws + (16u << 20));       // 16 MB
  unsigned short* ybuf = (unsigned short*)(ws + (32u << 20));       // 32 MB
  char* ctrl = ws + (64u << 20);
  int*   counts = (int*)ctrl;                                       // 32 B
  int*   ntiles = (int*)(ctrl + 64);                                // 4 B
  int*   done   = (int*)(ctrl + 96);                                // 4 B
  int*   offset = (int*)(ctrl + 128);                               // 32 B
  int*   desc   = (int*)(ctrl + 256);                               // 544 B
  int*   tok    = (int*)(ctrl + 4096);                              // 256 KB
  int2*  pos    = (int2*)(ctrl + 4096 + (256u << 10));              // 64 KB
  int4*  topk   = (int4*)(ctrl + 4096 + (320u << 10));              // 128 KB

  hipMemsetAsync(ctrl, 0, 128, stream);  // counts + ntiles + done

  router_kernel<<<RBLK, 256, 0, stream>>>(
      x, Wr, br, xbf, topk, counts, tok, pos, done, desc, ntiles, offset);
  wcast_kernel<<<WBLK, 256, 0, stream>>>(W, wt);
  // split GEMM: slots 0-63 (512 blocks), then 64-135 (576 blocks).
  moe_gemm_kernel<<<dim3(8, 64), 256, 0, stream>>>(
      xbf, wt, counts, offset, tok, desc, ntiles, ybuf, 0);
  moe_gemm_kernel<<<dim3(8, 72), 256, 0, stream>>>(
      xbf, wt, counts, offset, tok, desc, ntiles, ybuf, 64);
  combine_kernel<<<NTOK / 4, 256, 0, stream>>>(ybuf, topk, pos, offset, b, out);
}

// Round 9
// 196.246 us; speedup vs baseline: 1.1799x; 1.1690x over previous
//
#include <hip/hip_runtime.h>
#include <hip/hip_bf16.h>

// MoE: N=8192 tokens, D=1024, E=8 experts, top-2 routing.
// Inputs (fp32): x[8192,1024], Wr[1024,8], br[8], W[8,1024,1024], b[8,1024]
// Output (fp32): out[8192,1024]
//
// R1: block-aggregated scatter. R4: atomic-free epilogue + slot-major ybuf.
// R11: XCD remap (FETCH 118->85MB, kept); 2-phase dbuf regressed (reverted).
// R12: waterline split -> ROUTER EXPOSED: 58us, nothing busy (VALU 6.8%,
//     hbm 0.58 TB/s, occ 24%). Diagnosis: per-lane-divergent Wr gather
//     (64 lines/instr, L1 thrashed by streaming x, 32-VGPR serial chains).
// R13: router rebuilt around LDS-staged Wr:
//     - Wr -> LDS padded [1024][9] f32 (36KB); gather addr (i*64+l)*9+e ->
//       2-way bank alias = free. No L1 thrash, no LSU divergence.
//     - x read as lane-strided dwords (d=i*64+l, 256B/instr, 16 loads in
//       flight); xbf stored 128B/instr coalesced.
//     - tile-build back to its own tiny kernel (no done/threadfence).
//     - GEMM single launch again (R4 core + XCD remap). wcast/combine same.

#define NTOK 8192
#define DM   1024
#define NEXP 8
#define CAP  8192    // per-expert slot capacity (worst case)
#define MAXT 136     // max total m-tiles

#define RBLK 1024    // router blocks (8 tokens each)
#define WBLK 512     // wcast blocks (128d x 128h tiles): 8e * 8d * 8h

typedef __attribute__((ext_vector_type(8))) short bf16x8;
typedef __attribute__((ext_vector_type(4))) float f32x4;

__device__ __forceinline__ unsigned short f2bf(float f) {
  unsigned u = __float_as_uint(f);
  unsigned r = (u + 0x7fffu + ((u >> 16) & 1u)) >> 16;
  return (unsigned short)r;
}
__device__ __forceinline__ float bf2f(unsigned short s) {
  return __uint_as_float(((unsigned)s) << 16);
}

__device__ __forceinline__ void gl_lds16(const void* g, void* l) {
  __builtin_amdgcn_global_load_lds(
      (const __attribute__((address_space(1))) unsigned int*)g,
      (__attribute__((address_space(3))) unsigned int*)l, 16, 0, 0);
}

// ---------------- Router: logits via LDS-staged Wr, top-2, cast, scatter ---
// 1024 blocks x 256 thr; wave = 2 tokens; block = 8 tokens.
// LDS: Wr padded [1024][9] f32 = 36KB -> 4 blocks/CU, all 1024 resident.
__global__ __launch_bounds__(256) void router_kernel(
    const float* __restrict__ x, const float* __restrict__ Wr,
    const float* __restrict__ br, unsigned short* __restrict__ xbf,
    int4* __restrict__ topk, int* __restrict__ counts,
    int* __restrict__ tok, int2* __restrict__ pos) {
  __shared__ float sWr[1024 * 9];   // padded: row r at sWr[r*9], 9216 dwords
  __shared__ int  lcnt[NEXP];
  __shared__ int4 ltop[8];
  __shared__ int2 lrank[8];
  const int tid = threadIdx.x;
  const int wave = tid >> 6, lane = tid & 63;
  const int tb = blockIdx.x * 8 + wave * 2;   // this wave's 2 tokens
  if (tid < NEXP) lcnt[tid] = 0;

  // stage Wr -> LDS padded [1024][9]; global reads 32B/lane coalesced;
  // ds writes at 9-dword lane stride (2-way alias = free).
#pragma unroll
  for (int it = 0; it < 4; it++) {
    const int row = it * 256 + tid;
    float4 w0 = *(const float4*)(Wr + (size_t)row * 8);
    float4 w1 = *(const float4*)(Wr + (size_t)row * 8 + 4);
    float* dst = &sWr[row * 9];
    dst[0] = w0.x; dst[1] = w0.y; dst[2] = w0.z; dst[3] = w0.w;
    dst[4] = w1.x; dst[5] = w1.y; dst[6] = w1.z; dst[7] = w1.w;
  }
  __syncthreads();

  // per-token: lane owns d in {i*64 + lane}; 16 independent dword loads.
  float p[2][8] = {{0}};
#pragma unroll
  for (int tt = 0; tt < 2; tt++) {
    const float* xr = x + (size_t)(tb + tt) * DM + lane;
    float v[16];
#pragma unroll
    for (int i = 0; i < 16; i++) v[i] = xr[i * 64];        // 256B/instr
    unsigned short* xo = xbf + (size_t)(tb + tt) * DM + lane;
#pragma unroll
    for (int i = 0; i < 16; i++) xo[i * 64] = f2bf(v[i]);  // 128B/instr
#pragma unroll
    for (int i = 0; i < 16; i++) {
      const float* wrow = &sWr[(i * 64 + lane) * 9];       // 2-way banks
      float xv = v[i];
#pragma unroll
      for (int e = 0; e < 8; e++) p[tt][e] += xv * wrow[e];
    }
  }
#pragma unroll
  for (int off = 32; off >= 1; off >>= 1) {
#pragma unroll
    for (int tt = 0; tt < 2; tt++)
#pragma unroll
      for (int e = 0; e < 8; e++)
        p[tt][e] += __shfl_xor(p[tt][e], off, 64);
  }
  if (lane == 0) {
#pragma unroll
    for (int tt = 0; tt < 2; tt++) {
      float lg[8];
#pragma unroll
      for (int e = 0; e < 8; e++) lg[e] = p[tt][e] + br[e];
      float v0 = lg[0]; int i0 = 0;
#pragma unroll
      for (int e = 1; e < 8; e++) if (lg[e] > v0) { v0 = lg[e]; i0 = e; }
      float v1 = -3.4e38f; int i1 = 0;
#pragma unroll
      for (int e = 0; e < 8; e++)
        if (e != i0 && lg[e] > v1) { v1 = lg[e]; i1 = e; }
      float ee = __expf(v1 - v0);
      float g0 = 1.0f / (1.0f + ee);
      float g1 = ee / (1.0f + ee);
      int4 rec;
      rec.x = i0; rec.y = i1;
      rec.z = __float_as_int(g0); rec.w = __float_as_int(g1);
      ltop[wave * 2 + tt] = rec;
      topk[tb + tt] = rec;
    }
  }
  __syncthreads();

  if (tid < 8) {
    int4 r = ltop[tid];
    int s0 = atomicAdd(&lcnt[r.x], 1);
    int s1 = atomicAdd(&lcnt[r.y], 1);
    int2 rk; rk.x = s0; rk.y = s1;
    lrank[tid] = rk;
  }
  __syncthreads();
  if (tid < NEXP) lcnt[tid] = atomicAdd(&counts[tid], lcnt[tid]);
  __syncthreads();
  if (tid < 8) {
    int4 r = ltop[tid];
    int2 rk = lrank[tid];
    int p0 = lcnt[r.x] + rk.x;
    int p1 = lcnt[r.y] + rk.y;
    int t = blockIdx.x * 8 + tid;
    tok[r.x * CAP + p0] = t;
    tok[r.y * CAP + p1] = t;
    int2 pr; pr.x = p0; pr.y = p1;
    pos[t] = pr;
  }
}

// ---------------- Tile-descriptor build + expert offsets (tiny kernel) -----
__global__ __launch_bounds__(64) void build_tiles_kernel(
    const int* __restrict__ counts, int* __restrict__ desc,
    int* __restrict__ ntiles, int* __restrict__ offset) {
  if (threadIdx.x == 0) {
    int idx = 0, off = 0;
#pragma unroll
    for (int e = 0; e < NEXP; e++) {
      offset[e] = off;
      off += counts[e];
      int nm = (counts[e] + 127) >> 7;
      for (int i = 0; i < nm; i++) desc[idx++] = (e << 16) | i;
    }
    *ntiles = idx;
  }
}

// ---------------- W transpose + bf16 cast (R10 form, unchanged) ------------
__global__ __launch_bounds__(256) void wcast_kernel(
    const float* __restrict__ W, unsigned short* __restrict__ Wt) {
  __shared__ __align__(16) unsigned int smem[8192];  // 32 KB
  const int tid = threadIdx.x;
  const int tb = blockIdx.x;
  const int e = tb >> 6;
  const int rem = tb & 63;
  const int D0 = (rem >> 3) * 128;
  const int H0 = (rem & 7) * 128;

  const int dp = tid >> 5;          // 0..7
  const int c  = tid & 31;          // 0..31
  const float* Wsrc = W + (size_t)e * DM * DM + (size_t)D0 * DM + H0 + c * 4;
#pragma unroll 4
  for (int i = 0; i < 8; i++) {
    const int dc = dp + 8 * i;      // dword col 0..63 (d = 2dc, 2dc+1)
    const int d = dc * 2;
    float4 a = *(const float4*)(Wsrc + (size_t)d * DM);
    float4 b = *(const float4*)(Wsrc + (size_t)(d + 1) * DM);
    unsigned pk[4];
    pk[0] = (unsigned)f2bf(a.x) | ((unsigned)f2bf(b.x) << 16);
    pk[1] = (unsigned)f2bf(a.y) | ((unsigned)f2bf(b.y) << 16);
    pk[2] = (unsigned)f2bf(a.z) | ((unsigned)f2bf(b.z) << 16);
    pk[3] = (unsigned)f2bf(a.w) | ((unsigned)f2bf(b.w) << 16);
#pragma unroll
    for (int j = 0; j < 4; j++) {
      const int h = c * 4 + j;                       // 0..127
      const int pg = ((dc >> 2) ^ (h >> 2)) & 15;    // swizzled granule
      smem[h * 64 + pg * 4 + (dc & 3)] = pk[j];
    }
  }
  __syncthreads();

  const int hh = tid >> 4;   // 0..15
  const int g  = tid & 15;   // logical granule (8 bf16 of d)
  unsigned short* Wdst = Wt + (size_t)e * DM * DM + (size_t)H0 * DM + D0;
#pragma unroll 4
  for (int o = 0; o < 8; o++) {
    const int h = hh + 16 * o;                       // 0..127
    const int pg = (g ^ (h >> 2)) & 15;              // physical granule
    uint4 v = *(const uint4*)(smem + h * 64 + pg * 4);
    *(uint4*)(Wdst + (size_t)h * DM + g * 8) = v;
  }
}

// ---------------- Routed expert GEMM -> slot-major bf16 ybuf ----------------
// PROVEN R4 core (33KB LDS, 4 blk/CU) + XCD remap (FETCH 118->85MB).
__global__ __launch_bounds__(256) void moe_gemm_kernel(
    const unsigned short* __restrict__ xbf, const unsigned short* __restrict__ wt,
    const int* __restrict__ counts, const int* __restrict__ offset,
    const int* __restrict__ tok, const int* __restrict__ desc,
    const int* __restrict__ ntiles, unsigned short* __restrict__ ybuf) {
  // remap: linear L -> slot=(L&7)+8*(L>>6), nb=(L>>3)&7. The 8 n-blocks of a
  // slot have ids congruent mod 8 -> same XCD -> A-panel fetched once to L2.
  const int L = blockIdx.y * 8 + blockIdx.x;
  const int slot = (L & 7) | ((L >> 6) << 3);
  const int n0 = ((L >> 3) & 7) * 128;
  if (slot >= *ntiles) return;
  const int dsc = desc[slot];
  const int e = dsc >> 16;
  const int m0 = (dsc & 0xffff) * 128;
  const int cnt = counts[e];

  __shared__ __align__(16) unsigned short sA0[128 * 32];
  __shared__ __align__(16) unsigned short sB0[128 * 32];
  __shared__ __align__(16) unsigned short sA1[128 * 32];
  __shared__ __align__(16) unsigned short sB1[128 * 32];
  __shared__ int sTok[128];

  const int tid = threadIdx.x, wave = tid >> 6, lane = tid & 63;

  if (tid < 128) {
    int sr = m0 + tid;
    int cl = (sr < cnt) ? sr : (cnt - 1);
    sTok[tid] = tok[e * CAP + cl];
  }
  __syncthreads();

  const int rA1 = wave * 16 + (lane >> 2);
  const int rA2 = rA1 + 64;
  const int cch = lane & 3;
  const int cg1 = (cch ^ ((rA1 >> 1) & 3)) * 8;  // elements
  const int cg2 = (cch ^ ((rA2 >> 1) & 3)) * 8;
  const unsigned short* pA1 = xbf + (size_t)sTok[rA1] * DM + cg1;
  const unsigned short* pA2 = xbf + (size_t)sTok[rA2] * DM + cg2;
  const unsigned short* wte = wt + (size_t)e * DM * DM;
  const unsigned short* pB1 = wte + (size_t)(n0 + rA1) * DM + cg1;
  const unsigned short* pB2 = wte + (size_t)(n0 + rA2) * DM + cg2;
  const int lo1 = wave * 512, lo2 = (wave + 4) * 512;  // 1KB per 16-row group

  const int q = lane >> 4, ml = lane & 15;
  const int wm = (wave >> 1) * 64, wn = (wave & 1) * 64;
  int offA[4], offB[4];
#pragma unroll
  for (int i = 0; i < 4; i++) {
    int row = wm + i * 16 + ml;
    offA[i] = row * 32 + (q ^ ((row >> 1) & 3)) * 8;
    int rowb = wn + i * 16 + ml;
    offB[i] = rowb * 32 + (q ^ ((rowb >> 1) & 3)) * 8;
  }

  f32x4 acc[4][4] = {};

  for (int k0 = 0; k0 < DM; k0 += 64) {
    gl_lds16(pA1 + k0, sA0 + lo1);
    gl_lds16(pA2 + k0, sA0 + lo2);
    gl_lds16(pB1 + k0, sB0 + lo1);
    gl_lds16(pB2 + k0, sB0 + lo2);
    gl_lds16(pA1 + k0 + 32, sA1 + lo1);
    gl_lds16(pA2 + k0 + 32, sA1 + lo2);
    gl_lds16(pB1 + k0 + 32, sB1 + lo1);
    gl_lds16(pB2 + k0 + 32, sB1 + lo2);
    __syncthreads();
    bf16x8 af0[4], bf0[4], af1[4], bf1[4];
#pragma unroll
    for (int i = 0; i < 4; i++) {
      af0[i] = *(const bf16x8*)(sA0 + offA[i]);
      bf0[i] = *(const bf16x8*)(sB0 + offB[i]);
      af1[i] = *(const bf16x8*)(sA1 + offA[i]);
      bf1[i] = *(const bf16x8*)(sB1 + offB[i]);
    }
#pragma unroll
    for (int mt = 0; mt < 4; mt++)
#pragma unroll
      for (int nt = 0; nt < 4; nt++)
        acc[mt][nt] = __builtin_amdgcn_mfma_f32_16x16x32_bf16(
            af0[mt], bf0[nt], acc[mt][nt], 0, 0, 0);
#pragma unroll
    for (int mt = 0; mt < 4; mt++)
#pragma unroll
      for (int nt = 0; nt < 4; nt++)
        acc[mt][nt] = __builtin_amdgcn_mfma_f32_16x16x32_bf16(
            af1[mt], bf1[nt], acc[mt][nt], 0, 0, 0);
    __syncthreads();
  }

  const int yb = offset[e] + m0;
#pragma unroll
  for (int mt = 0; mt < 4; mt++) {
    int rbase = wm + mt * 16 + q * 4;
#pragma unroll
    for (int r = 0; r < 4; r++) {
      int row = rbase + r;
      if (m0 + row >= cnt) continue;
      unsigned short* yrow = ybuf + (size_t)(yb + row) * DM + n0;
#pragma unroll
      for (int nt = 0; nt < 4; nt++) {
        yrow[wn + nt * 16 + ml] = f2bf(acc[mt][nt][r]);
      }
    }
  }
}

// ---------------- Combine: out[t] = g0*(y0+b[e0]) + g1*(y1+b[e1]) -----------
__global__ __launch_bounds__(256) void combine_kernel(
    const unsigned short* __restrict__ ybuf, const int4* __restrict__ topk,
    const int2* __restrict__ pos, const int* __restrict__ offset,
    const float* __restrict__ bias, float* __restrict__ out) {
  const int c = threadIdx.x * 4;
  const int t0 = blockIdx.x * 4;
#pragma unroll
  for (int i = 0; i < 4; i++) {
    const int t = t0 + i;
    int4 r = topk[t];
    int2 p = pos[t];
    float g0 = __int_as_float(r.z), g1 = __int_as_float(r.w);
    int s0 = offset[r.x] + p.x;
    int s1 = offset[r.y] + p.y;
    ushort4 ya = *(const ushort4*)(ybuf + (size_t)s0 * DM + c);
    ushort4 yb = *(const ushort4*)(ybuf + (size_t)s1 * DM + c);
    float4 b0 = *(const float4*)(bias + (size_t)r.x * DM + c);
    float4 b1 = *(const float4*)(bias + (size_t)r.y * DM + c);
    float4 o;
    o.x = g0 * (bf2f(ya.x) + b0.x) + g1 * (bf2f(yb.x) + b1.x);
    o.y = g0 * (bf2f(ya.y) + b0.y) + g1 * (bf2f(yb.y) + b1.y);
    o.z = g0 * (bf2f(ya.z) + b0.z) + g1 * (bf2f(yb.z) + b1.z);
    o.w = g0 * (bf2f(ya.w) + b0.w) + g1 * (bf2f(yb.w) + b1.w);
    *(float4*)(out + (size_t)t * DM + c) = o;
  }
}

extern "C" void kernel_launch(void* const* d_in, const int* in_sizes, int n_in,
                              void* d_out, int out_size, void* d_ws, size_t ws_size,
                              hipStream_t stream) {
  const float* x  = (const float*)d_in[0];
  const float* Wr = (const float*)d_in[1];
  const float* br = (const float*)d_in[2];
  const float* W  = (const float*)d_in[3];
  const float* b  = (const float*)d_in[4];
  float* out = (float*)d_out;

  // workspace layout (~65.5 MB)
  char* ws = (char*)d_ws;
  unsigned short* xbf  = (unsigned short*)ws;                       // 16 MB
  unsigned short* wt   = (unsigned short*)(ws + (16u << 20));       // 16 MB
  unsigned short* ybuf = (unsigned short*)(ws + (32u << 20));       // 32 MB
  char* ctrl = ws + (64u << 20);
  int*   counts = (int*)ctrl;                                       // 32 B
  int*   ntiles = (int*)(ctrl + 64);                                // 4 B
  int*   offset = (int*)(ctrl + 128);                               // 32 B
  int*   desc   = (int*)(ctrl + 256);                               // 544 B
  int*   tok    = (int*)(ctrl + 4096);                              // 256 KB
  int2*  pos    = (int2*)(ctrl + 4096 + (256u << 10));              // 64 KB
  int4*  topk   = (int4*)(ctrl + 4096 + (320u << 10));              // 128 KB

  hipMemsetAsync(ctrl, 0, 128, stream);  // counts + ntiles

  router_kernel<<<RBLK, 256, 0, stream>>>(
      x, Wr, br, xbf, topk, counts, tok, pos);
  wcast_kernel<<<WBLK, 256, 0, stream>>>(W, wt);
  build_tiles_kernel<<<1, 64, 0, stream>>>(counts, desc, ntiles, offset);
  moe_gemm_kernel<<<dim3(8, MAXT), 256, 0, stream>>>(
      xbf, wt, counts, offset, tok, desc, ntiles, ybuf);
  combine_kernel<<<NTOK / 4, 256, 0, stream>>>(ybuf, topk, pos, offset, b, out);
}